// Round 1
// 393.439 us; speedup vs baseline: 1.0146x; 1.0146x over previous
//
#include <hip/hip_runtime.h>

typedef int v4i __attribute__((ext_vector_type(4)));
typedef int v16i __attribute__((ext_vector_type(16)));

#define IN_F   3072
#define PAD    4096
#define M_ROWS 8192
#define N_OUT  4096

#define BM 128
#define BN 256
#define BK 64

// ---------------------------------------------------------------------------
// async 16B global -> LDS copy. Integer round-trip casts: guaranteed to
// compile; LDS aperture on gfx9 is 4GB-aligned so low-32 truncation of the
// flat address IS the LDS offset. HW dest = wave-uniform base + lane*16.
// ---------------------------------------------------------------------------
__device__ __forceinline__ void async_copy16(const void* g, void* l) {
    __builtin_amdgcn_global_load_lds(
        (__attribute__((address_space(1))) const void*)(uintptr_t)g,
        (__attribute__((address_space(3))) void*)(uint32_t)(uintptr_t)l,
        16, 0, 0);
}

// unnormalized FWHT over 16 register values
__device__ __forceinline__ void fwht16(float v[16]) {
#pragma unroll
    for (int s = 1; s < 16; s <<= 1) {
#pragma unroll
        for (int i = 0; i < 16; i++) {
            if ((i & s) == 0) {
                float a = v[i], b = v[i ^ s];
                v[i]     = a + b;
                v[i ^ s] = a - b;
            }
        }
    }
}

// ---------------------------------------------------------------------------
// One row per block: load 3072 floats (zero-pad to 4096), FWHT-4096 as
// FWHT16 (x) FWHT16 (x) FWHT16 with two XOR-swizzled LDS exchanges
// (<=2-way bank aliasing on every access = free), then 8-bit affine
// quantize; store (q-128) as int8 and the row sum of (q-128).
// index decomposition: k = 256*k2 + 16*k1 + k0
// ---------------------------------------------------------------------------
__global__ __launch_bounds__(256) void fwht_quant_kernel(
    const float* __restrict__ in, signed char* __restrict__ qout,
    int* __restrict__ rowsum, int nrows)
{
    __shared__ float lds[4096];
    __shared__ int ssum;
    const int t = threadIdx.x;
    const int r = blockIdx.x;
    if (r >= nrows) return;
    const float* row = in + (size_t)r * IN_F;

    // load: reg j (=k2) holds element 256*j + t  (perfectly coalesced; 3072 = 12*256)
    float v[16];
#pragma unroll
    for (int j = 0; j < 16; j++)
        v[j] = (j < 12) ? row[j * 256 + t] : 0.0f;

    fwht16(v);                      // over k2

    const int th = t >> 4, tl = t & 15;   // (k1,k0) for now

    // exchange 1: layout phys(k2,k1,k0) = 256*k2 + 16*(k1^k2) + (k0^k1)
    #pragma unroll
    for (int j = 0; j < 16; j++)
        lds[256 * j + 16 * (th ^ j) + (tl ^ th)] = v[j];   // (k2=j,k1=th,k0=tl)
    __syncthreads();
#pragma unroll
    for (int j = 0; j < 16; j++)                            // now (k2=th,k0=tl), regs k1
        v[j] = lds[256 * th + 16 * (j ^ th) + (tl ^ j)];

    fwht16(v);                      // over k1

    if (t == 0) ssum = 0;
    __syncthreads();                // protects lds reuse + ssum init

    // exchange 2: layout phys(k2,k1,k0) = 256*k2 + 16*(k1^k2) + (k0^k1)
#pragma unroll
    for (int j = 0; j < 16; j++)                            // (k2=th,k1=j,k0=tl)
        lds[256 * th + 16 * (j ^ th) + (tl ^ j)] = v[j];
    __syncthreads();
#pragma unroll
    for (int j = 0; j < 16; j++)                            // now (k2=th,k1=tl), regs k0
        v[j] = lds[256 * th + 16 * (tl ^ th) + (j ^ tl)];

    fwht16(v);                      // over k0 -> thread t holds elements [16t,16t+16)

    // quantize: q = clip(round((clip(x,+-384)+384)/s),0,255); store a=q-128
    // 1/s = 255/768 = 85/256 exactly representable in f32
    const float INV = 0.33203125f;
    int sum = 0;
    int pk[4];
#pragma unroll
    for (int c = 0; c < 4; c++) {
        int word = 0;
#pragma unroll
        for (int b = 0; b < 4; b++) {
            float x = v[c * 4 + b];
            x = fminf(fmaxf(x, -384.0f), 384.0f);
            float qf = rintf((x + 384.0f) * INV);
            int qi = (int)qf;
            qi = qi < 0 ? 0 : (qi > 255 ? 255 : qi);
            int a = qi - 128;
            sum += a;
            word |= (a & 255) << (8 * b);
        }
        pk[c] = word;
    }

    // row-sum: wave shuffle reduce, then one LDS atomic per wave
#pragma unroll
    for (int off = 32; off > 0; off >>= 1) sum += __shfl_down(sum, off, 64);
    if ((t & 63) == 0) atomicAdd(&ssum, sum);

    ((int4*)(qout + (size_t)r * PAD))[t] = make_int4(pk[0], pk[1], pk[2], pk[3]);

    __syncthreads();
    if (t == 0) rowsum[r] = ssum;
}

// ---------------------------------------------------------------------------
// int8 GEMM: C[m,n] = sum_k A[m,k]*B[n,k] (both K-major), then affine fixup.
// Block tile 128x256, BK=64 bytes, 4 waves each 64x128 (2x4 mfma 32x32x32).
//
// LDS swizzle (v2): physical chunk p of row r stores logical chunk
// q = (p - (r>>1)) & 3. Fragment ds_read_b128 slot within the 128B bank
// window is (r&1)*64 + p*16 with p = (qbase + (r>>1))&3 -> any 8
// consecutive lanes cover all 8 slots exactly once = conflict-free.
// (The previous (p - r)&3 rotation had period 4 in lanes: 8-lane groups
// hit only 4 slots, 2 lanes each -> ~2x LDS serialization, 3.8e7
// SQ_LDS_BANK_CONFLICT per dispatch.)
// global_load_lds staging stays sequential-chunk by construction; the
// per-lane source address permutes only within each row's 64B segment.
//
// Pipeline (v2): 3 LDS buffers (72 KB, 2 blocks/CU), prefetch depth 2,
// counted s_waitcnt vmcnt(6) (= 6 gload_lds/wave/tile; the 6 newest in
// flight are tile t+2's) + raw s_barrier per iteration. Never drains
// vmcnt to 0 in the main loop, so HBM latency hides under two compute
// iterations. asm memory clobbers fence both sides of each barrier so
// neither stage writes nor ds_reads can be moved across it.
//
// epilogue: out = D*kA + (SA[m]+SB[n])*kS + kC + bias[n]
// ---------------------------------------------------------------------------
__global__ __launch_bounds__(256, 2) void gemm_i8_kernel(
    const signed char* __restrict__ A, const signed char* __restrict__ B,
    const int* __restrict__ SA, const int* __restrict__ SB,
    const float* __restrict__ bias, float* __restrict__ out,
    float kA, float kS, float kC)
{
    __shared__ __align__(16) signed char As[3][BM * BK];   // 3 x 8 KB
    __shared__ __align__(16) signed char Bs[3][BN * BK];   // 3 x 16 KB

    const int tid  = threadIdx.x;
    const int lane = tid & 63;
    const int wid  = tid >> 6;
    const int wr   = wid >> 1, wc = wid & 1;
    const int bm   = blockIdx.y * BM;
    const int bn   = blockIdx.x * BN;
    const int l5   = lane >> 5;     // 0/1 half-wave
    const int lm   = lane & 31;     // mfma row/col lane

    v16i acc[2][4];
#pragma unroll
    for (int i = 0; i < 2; i++)
#pragma unroll
        for (int j = 0; j < 4; j++)
#pragma unroll
            for (int e = 0; e < 16; e++)
                acc[i][j][e] = 0;

    // stage tile kt into buffer b: 6 gload_lds per wave (2 A + 4 B)
    auto stage = [&](int b, int kt) {
        const int bk = kt * BK;
#pragma unroll
        for (int i = 0; i < 2; i++) {
            int c = wid * 128 + i * 64 + lane;
            int rr = c >> 2, p = c & 3;
            int q = (p - (rr >> 1)) & 3;          // logical chunk stored at p
            async_copy16(A + (size_t)(bm + rr) * PAD + bk + q * 16,
                         As[b] + (wid * 128 + i * 64) * 16);
        }
#pragma unroll
        for (int i = 0; i < 4; i++) {
            int c = wid * 256 + i * 64 + lane;
            int rr = c >> 2, p = c & 3;
            int q = (p - (rr >> 1)) & 3;
            async_copy16(B + (size_t)(bn + rr) * PAD + bk + q * 16,
                         Bs[b] + (wid * 256 + i * 64) * 16);
        }
    };

    // compute one K-tile from buffer b: 2 k-steps of 32, 8 mfma each
    auto compute = [&](int b) {
#pragma unroll
        for (int ks = 0; ks < 2; ks++) {
            const int qbase = ks * 2 + l5;         // logical 16B chunk wanted
            v4i af[2], bf[4];
#pragma unroll
            for (int mt = 0; mt < 2; mt++) {
                int rr = wr * 64 + mt * 32 + lm;
                int p = (qbase + (rr >> 1)) & 3;
                af[mt] = *(const v4i*)(As[b] + rr * 64 + p * 16);
            }
#pragma unroll
            for (int nt = 0; nt < 4; nt++) {
                int rr = wc * 128 + nt * 32 + lm;
                int p = (qbase + (rr >> 1)) & 3;
                bf[nt] = *(const v4i*)(Bs[b] + rr * 64 + p * 16);
            }
            __builtin_amdgcn_s_setprio(1);
#pragma unroll
            for (int mt = 0; mt < 2; mt++)
#pragma unroll
                for (int nt = 0; nt < 4; nt++)
                    acc[mt][nt] = __builtin_amdgcn_mfma_i32_32x32x32_i8(
                        af[mt], bf[nt], acc[mt][nt], 0, 0, 0);
            __builtin_amdgcn_s_setprio(0);
        }
    };

    constexpr int T = PAD / BK;    // 64 K-tiles

    // prologue: fill 2 tiles, wait for tile 0 (tile 1's 6 loads stay in flight)
    stage(0, 0);
    stage(1, 1);
    asm volatile("s_waitcnt vmcnt(6)" ::: "memory");
    __builtin_amdgcn_s_barrier();
    asm volatile("" ::: "memory");

    int b0 = 0, b1 = 1, b2 = 2;
    for (int t = 0; t < T; ++t) {
        if (t + 2 < T) stage(b2, t + 2);           // prefetch depth 2
        compute(b0);
        if (t < T - 1) {
            if (t + 2 < T)
                asm volatile("s_waitcnt vmcnt(6)" ::: "memory");  // t+1 done, t+2 in flight
            else
                asm volatile("s_waitcnt vmcnt(0)" ::: "memory");  // drain only at tail
            __builtin_amdgcn_s_barrier();
            asm volatile("" ::: "memory");
        }
        int tmp = b0; b0 = b1; b1 = b2; b2 = tmp;
    }

    // ---- epilogue: C/D layout col=lane&31, row=(e&3)+8*(e>>2)+4*(lane>>5) ----
#pragma unroll
    for (int nt = 0; nt < 4; nt++) {
        int n = bn + wc * 128 + nt * 32 + lm;
        float ct = (float)SB[n] * kS + kC + bias[n];
#pragma unroll
        for (int mt = 0; mt < 2; mt++) {
#pragma unroll
            for (int e = 0; e < 16; e++) {
                int m = bm + wr * 64 + mt * 32 + l5 * 4 + (e & 3) + 8 * (e >> 2);
                out[(size_t)m * N_OUT + n] =
                    (float)acc[mt][nt][e] * kA + (float)SA[m] * kS + ct;
            }
        }
    }
}

// ---------------------------------------------------------------------------
extern "C" void kernel_launch(void* const* d_in, const int* in_sizes, int n_in,
                              void* d_out, int out_size, void* d_ws, size_t ws_size,
                              hipStream_t stream) {
    const float* x    = (const float*)d_in[0];   // [2,4096,3072]
    const float* w    = (const float*)d_in[1];   // [4096,3072]
    const float* bias = (const float*)d_in[2];   // [4096]
    float* out = (float*)d_out;                  // [2,4096,4096]

    // workspace: qa 32MB | qb 16MB | SA 32KB | SB 16KB  (~48MB total)
    signed char* qa = (signed char*)d_ws;
    signed char* qb = qa + (size_t)M_ROWS * PAD;
    int* SA = (int*)(qb + (size_t)N_OUT * PAD);
    int* SB = SA + M_ROWS;

    fwht_quant_kernel<<<M_ROWS, 256, 0, stream>>>(x, qa, SA, M_ROWS);
    fwht_quant_kernel<<<N_OUT,  256, 0, stream>>>(w, qb, SB, N_OUT);

    // out = (s^2*D + s*c*(SA+SB) + K*c^2)/K + bias,  s=768/255, c=128s-384=384/255
    double s = 768.0 / 255.0;
    double c = 384.0 / 255.0;
    float kA = (float)(s * s / PAD);
    float kS = (float)(s * c / PAD);
    float kC = (float)(c * c);

    dim3 grid(N_OUT / BN, M_ROWS / BM);
    gemm_i8_kernel<<<grid, 256, 0, stream>>>(qa, qb, SA, SB, bias, out, kA, kS, kC);
}

// Round 3
// 373.486 us; speedup vs baseline: 1.0688x; 1.0534x over previous
//
#include <hip/hip_runtime.h>

typedef int v4i __attribute__((ext_vector_type(4)));
typedef int v16i __attribute__((ext_vector_type(16)));

#define IN_F   3072
#define PAD    4096
#define M_ROWS 8192
#define N_OUT  4096

#define BM 256
#define BN 256
#define BK 64
#define TBUF (BM * BK)   // 16 KB per A/B tile buffer
#define TTILES (PAD / BK) // 64 K-tiles

// ---------------------------------------------------------------------------
// async 16B global -> LDS copy. Integer round-trip casts: guaranteed to
// compile; LDS aperture on gfx9 is 4GB-aligned so low-32 truncation of the
// flat address IS the LDS offset. HW dest = wave-uniform base + lane*16.
// ---------------------------------------------------------------------------
__device__ __forceinline__ void async_copy16(const void* g, void* l) {
    __builtin_amdgcn_global_load_lds(
        (__attribute__((address_space(1))) const void*)(uintptr_t)g,
        (__attribute__((address_space(3))) void*)(uint32_t)(uintptr_t)l,
        16, 0, 0);
}

// unnormalized FWHT over 16 register values
__device__ __forceinline__ void fwht16(float v[16]) {
#pragma unroll
    for (int s = 1; s < 16; s <<= 1) {
#pragma unroll
        for (int i = 0; i < 16; i++) {
            if ((i & s) == 0) {
                float a = v[i], b = v[i ^ s];
                v[i]     = a + b;
                v[i ^ s] = a - b;
            }
        }
    }
}

// ---------------------------------------------------------------------------
// One row per block: load 3072 floats (zero-pad to 4096), FWHT-4096 as
// FWHT16 (x) FWHT16 (x) FWHT16 with two XOR-swizzled LDS exchanges
// (<=2-way bank aliasing on every access = free), then 8-bit affine
// quantize; store (q-128) as int8 and the row sum of (q-128).
// index decomposition: k = 256*k2 + 16*k1 + k0
// ---------------------------------------------------------------------------
__global__ __launch_bounds__(256) void fwht_quant_kernel(
    const float* __restrict__ in, signed char* __restrict__ qout,
    int* __restrict__ rowsum, int nrows)
{
    __shared__ float lds[4096];
    __shared__ int ssum;
    const int t = threadIdx.x;
    const int r = blockIdx.x;
    if (r >= nrows) return;
    const float* row = in + (size_t)r * IN_F;

    // load: reg j (=k2) holds element 256*j + t  (perfectly coalesced; 3072 = 12*256)
    float v[16];
#pragma unroll
    for (int j = 0; j < 16; j++)
        v[j] = (j < 12) ? row[j * 256 + t] : 0.0f;

    fwht16(v);                      // over k2

    const int th = t >> 4, tl = t & 15;   // (k1,k0) for now

    // exchange 1: layout phys(k2,k1,k0) = 256*k2 + 16*(k1^k2) + (k0^k1)
    #pragma unroll
    for (int j = 0; j < 16; j++)
        lds[256 * j + 16 * (th ^ j) + (tl ^ th)] = v[j];   // (k2=j,k1=th,k0=tl)
    __syncthreads();
#pragma unroll
    for (int j = 0; j < 16; j++)                            // now (k2=th,k0=tl), regs k1
        v[j] = lds[256 * th + 16 * (j ^ th) + (tl ^ j)];

    fwht16(v);                      // over k1

    if (t == 0) ssum = 0;
    __syncthreads();                // protects lds reuse + ssum init

    // exchange 2: layout phys(k2,k1,k0) = 256*k2 + 16*(k1^k2) + (k0^k1)
#pragma unroll
    for (int j = 0; j < 16; j++)                            // (k2=th,k1=j,k0=tl)
        lds[256 * th + 16 * (j ^ th) + (tl ^ j)] = v[j];
    __syncthreads();
#pragma unroll
    for (int j = 0; j < 16; j++)                            // now (k2=th,k1=tl), regs k0
        v[j] = lds[256 * th + 16 * (tl ^ th) + (j ^ tl)];

    fwht16(v);                      // over k0 -> thread t holds elements [16t,16t+16)

    // quantize: q = clip(round((clip(x,+-384)+384)/s),0,255); store a=q-128
    // 1/s = 255/768 = 85/256 exactly representable in f32
    const float INV = 0.33203125f;
    int sum = 0;
    int pk[4];
#pragma unroll
    for (int c = 0; c < 4; c++) {
        int word = 0;
#pragma unroll
        for (int b = 0; b < 4; b++) {
            float x = v[c * 4 + b];
            x = fminf(fmaxf(x, -384.0f), 384.0f);
            float qf = rintf((x + 384.0f) * INV);
            int qi = (int)qf;
            qi = qi < 0 ? 0 : (qi > 255 ? 255 : qi);
            int a = qi - 128;
            sum += a;
            word |= (a & 255) << (8 * b);
        }
        pk[c] = word;
    }

    // row-sum: wave shuffle reduce, then one LDS atomic per wave
#pragma unroll
    for (int off = 32; off > 0; off >>= 1) sum += __shfl_down(sum, off, 64);
    if ((t & 63) == 0) atomicAdd(&ssum, sum);

    ((int4*)(qout + (size_t)r * PAD))[t] = make_int4(pk[0], pk[1], pk[2], pk[3]);

    __syncthreads();
    if (t == 0) rowsum[r] = ssum;
}

// ---------------------------------------------------------------------------
// int8 GEMM v3: 8-phase-style schedule (4 phases per K-tile).
// C[m,n] = sum_k A[m,k]*B[n,k] (both K-major), then affine fixup.
//
// Tile 256x256, BK=64 bytes. 8 waves in a 2M x 4N grid; per-wave output
// 128x64 = acc[4][2] of mfma 32x32x32 i8. LDS: triple-buffered 16KB A +
// 16KB B tiles = 96 KB -> 1 block/CU, 2 waves/SIMD (same occupancy shape
// as the verified bf16 8-phase template).
//
// LDS chunk-rotation swizzle (proven conflict-free in v2): physical 16B
// chunk p of row r holds logical chunk q = (p - (r>>1)) & 3; fragment
// ds_read_b128 slot in the 128B window is (r&1)*64 + p*16 -> any 8
// consecutive lanes cover all 8 slots exactly once.
//
// Schedule per K-tile t (computing from buf b0, prefetching t+2 into b2):
//   iteration top: load all 4 B-frags (register-resident for the K-tile)
//   phase q=0..3: { ds_read A-frags(mt=q) ; issue 1 of 4 global_load_lds
//     for tile t+2 ; setprio(1) ; 4 MFMA (mt=q, nt=0..1, ks=0..1) ;
//     setprio(0) ; [phase 3 only: s_waitcnt vmcnt(4)] ; s_barrier }
// vmcnt(4) BEFORE the tile-boundary barrier: after the barrier every
// wave's tile-t+1 staging has landed (vmcnt is per-wave; the barrier
// publishes all waves' waits). Never drains vmcnt in the main loop.
// Buffer-reuse hazard: reads of b2 (= b0 of iter t-2) completed via the
// compiler's lgkmcnt before that iter's MFMAs, two barriers before any
// staging writes into it.
//
// epilogue: out = D*kA + (SA[m]+SB[n])*kS + kC + bias[n]
// ---------------------------------------------------------------------------
__global__ __launch_bounds__(512, 2) void gemm_i8_kernel(
    const signed char* __restrict__ A, const signed char* __restrict__ B,
    const int* __restrict__ SA, const int* __restrict__ SB,
    const float* __restrict__ bias, float* __restrict__ out,
    float kA, float kS, float kC)
{
    __shared__ __align__(16) signed char As[3 * TBUF];
    __shared__ __align__(16) signed char Bs[3 * TBUF];

    const int tid  = threadIdx.x;
    const int lane = tid & 63;
    const int wid  = tid >> 6;          // 0..7
    const int wr   = wid >> 2;          // 0..1 (M)
    const int wc   = wid & 3;           // 0..3 (N)
    const int l5   = lane >> 5;
    const int lm   = lane & 31;

    // XCD-aware swizzle: grid=512, nwg%8==0. XCD k (= bid%8) gets 64
    // consecutive logical ids = 4 consecutive 256-row A panels (4MB ~ L2).
    const int bid = (int)blockIdx.x;
    const int swz = ((bid & 7) << 6) | (bid >> 3);
    const int bm  = (swz >> 4) * BM;
    const int bn  = (swz & 15) * BN;

    v16i acc[4][2];
#pragma unroll
    for (int i = 0; i < 4; i++)
#pragma unroll
        for (int j = 0; j < 2; j++)
#pragma unroll
            for (int e = 0; e < 16; e++)
                acc[i][j][e] = 0;

    // ---- staging addressing (per-lane constants) ----
    // A: 1024 chunks, 2 gload/wave; B: same. c = wid*128 + i*64 + lane.
    const signed char* srcA[2];
    const signed char* srcB[2];
    int dstO[2];
#pragma unroll
    for (int i = 0; i < 2; i++) {
        int c  = wid * 128 + i * 64 + lane;
        int rr = c >> 2, p = c & 3;
        int q  = (p - (rr >> 1)) & 3;          // logical chunk stored at p
        srcA[i] = A + (size_t)(bm + rr) * PAD + q * 16;
        srcB[i] = B + (size_t)(bn + rr) * PAD + q * 16;
        dstO[i] = (wid * 128 + i * 64) * 16;   // wave-uniform LDS base
    }

    // ---- fragment read offsets (per-lane constants) ----
    int aoff[4][2], boff[2][2];
#pragma unroll
    for (int mt = 0; mt < 4; mt++) {
        int rr = wr * 128 + mt * 32 + lm;
#pragma unroll
        for (int ks = 0; ks < 2; ks++) {
            int p = (ks * 2 + l5 + (rr >> 1)) & 3;
            aoff[mt][ks] = rr * 64 + p * 16;
        }
    }
#pragma unroll
    for (int nt = 0; nt < 2; nt++) {
        int rr = wc * 64 + nt * 32 + lm;
#pragma unroll
        for (int ks = 0; ks < 2; ks++) {
            int p = (ks * 2 + l5 + (rr >> 1)) & 3;
            boff[nt][ks] = rr * 64 + p * 16;
        }
    }

    // ---- prologue: stage tiles 0 and 1; wait tile 0 (tile 1 in flight) ----
#pragma unroll
    for (int i = 0; i < 2; i++) async_copy16(srcA[i],      As + dstO[i]);
#pragma unroll
    for (int i = 0; i < 2; i++) async_copy16(srcB[i],      Bs + dstO[i]);
#pragma unroll
    for (int i = 0; i < 2; i++) async_copy16(srcA[i] + BK, As + TBUF + dstO[i]);
#pragma unroll
    for (int i = 0; i < 2; i++) async_copy16(srcB[i] + BK, Bs + TBUF + dstO[i]);
    asm volatile("s_waitcnt vmcnt(4)" ::: "memory");
    __builtin_amdgcn_s_barrier();
    asm volatile("" ::: "memory");

    int ob0 = 0, ob1 = TBUF, ob2 = 2 * TBUF;

    for (int t = 0; t < TTILES; ++t) {
        const signed char* Ab = As + ob0;
        const signed char* Bb = Bs + ob0;
        const int  pk = (t + 2) * BK;
        const bool pf = (t + 2 < TTILES);

        // B-frags for the whole K-tile, register-resident
        v4i bfr[2][2];
#pragma unroll
        for (int nt = 0; nt < 2; nt++)
#pragma unroll
            for (int ks = 0; ks < 2; ks++)
                bfr[nt][ks] = *(const v4i*)(Bb + boff[nt][ks]);

        // ---- phase 0: mt=0, prefetch A-half 0 ----
        {
            v4i x0 = *(const v4i*)(Ab + aoff[0][0]);
            v4i x1 = *(const v4i*)(Ab + aoff[0][1]);
            if (pf) async_copy16(srcA[0] + pk, As + ob2 + dstO[0]);
            __builtin_amdgcn_s_setprio(1);
            acc[0][0] = __builtin_amdgcn_mfma_i32_32x32x32_i8(x0, bfr[0][0], acc[0][0], 0, 0, 0);
            acc[0][1] = __builtin_amdgcn_mfma_i32_32x32x32_i8(x0, bfr[1][0], acc[0][1], 0, 0, 0);
            acc[0][0] = __builtin_amdgcn_mfma_i32_32x32x32_i8(x1, bfr[0][1], acc[0][0], 0, 0, 0);
            acc[0][1] = __builtin_amdgcn_mfma_i32_32x32x32_i8(x1, bfr[1][1], acc[0][1], 0, 0, 0);
            __builtin_amdgcn_s_setprio(0);
            __builtin_amdgcn_s_barrier();
            asm volatile("" ::: "memory");
        }
        // ---- phase 1: mt=1, prefetch A-half 1 ----
        {
            v4i x0 = *(const v4i*)(Ab + aoff[1][0]);
            v4i x1 = *(const v4i*)(Ab + aoff[1][1]);
            if (pf) async_copy16(srcA[1] + pk, As + ob2 + dstO[1]);
            __builtin_amdgcn_s_setprio(1);
            acc[1][0] = __builtin_amdgcn_mfma_i32_32x32x32_i8(x0, bfr[0][0], acc[1][0], 0, 0, 0);
            acc[1][1] = __builtin_amdgcn_mfma_i32_32x32x32_i8(x0, bfr[1][0], acc[1][1], 0, 0, 0);
            acc[1][0] = __builtin_amdgcn_mfma_i32_32x32x32_i8(x1, bfr[0][1], acc[1][0], 0, 0, 0);
            acc[1][1] = __builtin_amdgcn_mfma_i32_32x32x32_i8(x1, bfr[1][1], acc[1][1], 0, 0, 0);
            __builtin_amdgcn_s_setprio(0);
            __builtin_amdgcn_s_barrier();
            asm volatile("" ::: "memory");
        }
        // ---- phase 2: mt=2, prefetch B-half 0 ----
        {
            v4i x0 = *(const v4i*)(Ab + aoff[2][0]);
            v4i x1 = *(const v4i*)(Ab + aoff[2][1]);
            if (pf) async_copy16(srcB[0] + pk, Bs + ob2 + dstO[0]);
            __builtin_amdgcn_s_setprio(1);
            acc[2][0] = __builtin_amdgcn_mfma_i32_32x32x32_i8(x0, bfr[0][0], acc[2][0], 0, 0, 0);
            acc[2][1] = __builtin_amdgcn_mfma_i32_32x32x32_i8(x0, bfr[1][0], acc[2][1], 0, 0, 0);
            acc[2][0] = __builtin_amdgcn_mfma_i32_32x32x32_i8(x1, bfr[0][1], acc[2][0], 0, 0, 0);
            acc[2][1] = __builtin_amdgcn_mfma_i32_32x32x32_i8(x1, bfr[1][1], acc[2][1], 0, 0, 0);
            __builtin_amdgcn_s_setprio(0);
            __builtin_amdgcn_s_barrier();
            asm volatile("" ::: "memory");
        }
        // ---- phase 3: mt=3, prefetch B-half 1, tile-boundary wait ----
        {
            v4i x0 = *(const v4i*)(Ab + aoff[3][0]);
            v4i x1 = *(const v4i*)(Ab + aoff[3][1]);
            if (pf) async_copy16(srcB[1] + pk, Bs + ob2 + dstO[1]);
            __builtin_amdgcn_s_setprio(1);
            acc[3][0] = __builtin_amdgcn_mfma_i32_32x32x32_i8(x0, bfr[0][0], acc[3][0], 0, 0, 0);
            acc[3][1] = __builtin_amdgcn_mfma_i32_32x32x32_i8(x0, bfr[1][0], acc[3][1], 0, 0, 0);
            acc[3][0] = __builtin_amdgcn_mfma_i32_32x32x32_i8(x1, bfr[0][1], acc[3][0], 0, 0, 0);
            acc[3][1] = __builtin_amdgcn_mfma_i32_32x32x32_i8(x1, bfr[1][1], acc[3][1], 0, 0, 0);
            __builtin_amdgcn_s_setprio(0);
            if (t < TTILES - 1) {
                if (pf) asm volatile("s_waitcnt vmcnt(4)" ::: "memory");
                else    asm volatile("s_waitcnt vmcnt(0)" ::: "memory");
                __builtin_amdgcn_s_barrier();
                asm volatile("" ::: "memory");
            }
        }

        int tmp = ob0; ob0 = ob1; ob1 = ob2; ob2 = tmp;
    }

    // ---- epilogue: C/D layout col=lane&31, row=(e&3)+8*(e>>2)+4*(lane>>5) ----
#pragma unroll
    for (int nt = 0; nt < 2; nt++) {
        int n = bn + wc * 64 + nt * 32 + lm;
        float ct = (float)SB[n] * kS + kC + bias[n];
#pragma unroll
        for (int mt = 0; mt < 4; mt++) {
#pragma unroll
            for (int e = 0; e < 16; e++) {
                int m = bm + wr * 128 + mt * 32 + l5 * 4 + (e & 3) + 8 * (e >> 2);
                out[(size_t)m * N_OUT + n] =
                    (float)acc[mt][nt][e] * kA + (float)SA[m] * kS + ct;
            }
        }
    }
}

// ---------------------------------------------------------------------------
extern "C" void kernel_launch(void* const* d_in, const int* in_sizes, int n_in,
                              void* d_out, int out_size, void* d_ws, size_t ws_size,
                              hipStream_t stream) {
    const float* x    = (const float*)d_in[0];   // [2,4096,3072]
    const float* w    = (const float*)d_in[1];   // [4096,3072]
    const float* bias = (const float*)d_in[2];   // [4096]
    float* out = (float*)d_out;                  // [2,4096,4096]

    // workspace: qa 32MB | qb 16MB | SA 32KB | SB 16KB  (~48MB total)
    signed char* qa = (signed char*)d_ws;
    signed char* qb = qa + (size_t)M_ROWS * PAD;
    int* SA = (int*)(qb + (size_t)N_OUT * PAD);
    int* SB = SA + M_ROWS;

    fwht_quant_kernel<<<M_ROWS, 256, 0, stream>>>(x, qa, SA, M_ROWS);
    fwht_quant_kernel<<<N_OUT,  256, 0, stream>>>(w, qb, SB, N_OUT);

    // out = (s^2*D + s*c*(SA+SB) + K*c^2)/K + bias,  s=768/255, c=128s-384=384/255
    double s = 768.0 / 255.0;
    double c = 384.0 / 255.0;
    float kA = (float)(s * s / PAD);
    float kS = (float)(s * c / PAD);
    float kC = (float)(c * c);

    dim3 grid((M_ROWS / BM) * (N_OUT / BN));     // 512 blocks, 1D for swizzle
    gemm_i8_kernel<<<grid, 512, 0, stream>>>(qa, qb, SA, SB, bias, out, kA, kS, kC);
}